// Round 5
// baseline (284.569 us; speedup 1.0000x reference)
//
#include <hip/hip_runtime.h>
#include <math.h>

#define SEQ 4096
#define DM  1024
#define NH  16
#define DK  64

typedef __attribute__((ext_vector_type(4))) float f32x4;
typedef __attribute__((ext_vector_type(8))) short bf16x8;
typedef __attribute__((ext_vector_type(8))) unsigned short u16x8;

union FragU { u16x8 u; bf16x8 b; ushort4 q[2]; unsigned w[4]; };

__device__ __forceinline__ unsigned cvtpk(float a, float b) {
    unsigned r; asm("v_cvt_pk_bf16_f32 %0, %1, %2" : "=v"(r) : "v"(a), "v"(b)); return r;
}
__device__ __forceinline__ float fexp2(float x) {
    float r; asm("v_exp_f32 %0, %1" : "=v"(r) : "v"(x)); return r;
}
__device__ __forceinline__ void split4(float4 v, ushort4& hv, ushort4& lv) {
    union { ushort4 q; unsigned w[2]; } H, L;
    H.w[0] = cvtpk(v.x, v.y); H.w[1] = cvtpk(v.z, v.w);
    const float rx = v.x - __uint_as_float(H.w[0] << 16);
    const float ry = v.y - __uint_as_float(H.w[0] & 0xffff0000u);
    const float rz = v.z - __uint_as_float(H.w[1] << 16);
    const float rw = v.w - __uint_as_float(H.w[1] & 0xffff0000u);
    L.w[0] = cvtpk(rx, ry); L.w[1] = cvtpk(rz, rw);
    hv = H.q; lv = L.q;
}
__device__ __forceinline__ void split1(float f, unsigned short& h, unsigned short& l) {
    const unsigned hw = cvtpk(f, f) & 0xffffu;
    h = (unsigned short)hw;
    const float r = f - __uint_as_float(hw << 16);
    l = (unsigned short)(__float_as_uint(r) >> 16);
}

// ---------------------------------------------------------------------------
// MFMA GEMM, 3-term bf16 hi/lo emulation. C = A * W^T.   (unchanged from R4)
// MODE 4: fused QKV. A = x fp32 [4096][1024]; W0/1/2 = Wq/Wk/Wv.
// MODE 0: Wo. A = pre-split y (Ahi/Alo bf16) -> fp32 out [4096][1024].
// Tile 128x128, BK=32, 4 waves (64x64 each, acc[4][4]).
// ---------------------------------------------------------------------------
template<int MODE>
__global__ __launch_bounds__(256, 2)
void gemm_mfma(const float* __restrict__ Af,
               const unsigned short* __restrict__ Ahi, const unsigned short* __restrict__ Alo,
               const float* __restrict__ W0, const float* __restrict__ W1,
               const float* __restrict__ W2,
               unsigned short* __restrict__ OQh, unsigned short* __restrict__ OQl,
               unsigned short* __restrict__ OKh, unsigned short* __restrict__ OKl,
               unsigned short* __restrict__ OVh, unsigned short* __restrict__ OVl,
               float* __restrict__ Ofp,
               const float* __restrict__ cosT, const float* __restrict__ sinT,
               const int* __restrict__ positions)
{
    constexpr int NT = (MODE == 4) ? 24 : 8;   // n-tiles of 128
    __shared__ unsigned short As[128][76];
    __shared__ unsigned short Bs[128][76];

    const int t   = threadIdx.x;
    const int bid = blockIdx.x;
    const int qpx = (32 * NT) >> 3;                 // blocks per XCD
    const int swz = (bid & 7) * qpx + (bid >> 3);   // XCD swizzle (nwg%8==0)
    const int by  = swz / NT;
    const int bxf = swz % NT;
    const int wt  = (MODE == 4) ? (bxf >> 3) : 0;
    const int bx  = (MODE == 4) ? (bxf & 7) : bxf;
    const int m0  = by * 128;
    const float* W = (MODE == 4) ? (wt == 0 ? W0 : (wt == 1 ? W1 : W2)) : W0;

    const int lane = t & 63, w = t >> 6;
    const int wr = w >> 1, wc = w & 1;
    const int l15 = lane & 15, lg = lane >> 4;

    const int ar = t >> 1, ah = t & 1;
    const float* Ap = (MODE == 4) ? &Af[(size_t)(m0 + ar) * DM + ah * 16] : nullptr;
    const unsigned short* Aph = (MODE == 0) ? &Ahi[(size_t)(m0 + ar) * DM + ah * 16] : nullptr;
    const unsigned short* Apl = (MODE == 0) ? &Alo[(size_t)(m0 + ar) * DM + ah * 16] : nullptr;
    const float* Wp = &W[(size_t)(bx * 128 + ar) * DM + ah * 16];

    f32x4 acc[4][4];
#pragma unroll
    for (int mi = 0; mi < 4; ++mi)
#pragma unroll
        for (int ni = 0; ni < 4; ++ni) acc[mi][ni] = (f32x4){0.f, 0.f, 0.f, 0.f};

    float4 pa[4], pb[4];
    u16x8 pah[2], pal[2];
    if constexpr (MODE == 4) {
#pragma unroll
        for (int g = 0; g < 4; ++g) pa[g] = *reinterpret_cast<const float4*>(Ap + g * 4);
    } else {
        pah[0] = *reinterpret_cast<const u16x8*>(Aph);
        pah[1] = *reinterpret_cast<const u16x8*>(Aph + 8);
        pal[0] = *reinterpret_cast<const u16x8*>(Apl);
        pal[1] = *reinterpret_cast<const u16x8*>(Apl + 8);
    }
#pragma unroll
    for (int g = 0; g < 4; ++g) pb[g] = *reinterpret_cast<const float4*>(Wp + g * 4);

    for (int kt = 0; kt < 32; ++kt) {
        if constexpr (MODE == 4) {
#pragma unroll
            for (int g = 0; g < 4; ++g) {
                ushort4 hv, lv;
                split4(pa[g], hv, lv);
                *reinterpret_cast<ushort4*>(&As[ar][8 * g + 4 * ah])      = hv;
                *reinterpret_cast<ushort4*>(&As[ar][32 + 8 * g + 4 * ah]) = lv;
            }
        } else {
            FragU h0, h1, l0, l1;
            h0.u = pah[0]; h1.u = pah[1]; l0.u = pal[0]; l1.u = pal[1];
            *reinterpret_cast<ushort4*>(&As[ar][0  + 4 * ah]) = h0.q[0];
            *reinterpret_cast<ushort4*>(&As[ar][8  + 4 * ah]) = h0.q[1];
            *reinterpret_cast<ushort4*>(&As[ar][16 + 4 * ah]) = h1.q[0];
            *reinterpret_cast<ushort4*>(&As[ar][24 + 4 * ah]) = h1.q[1];
            *reinterpret_cast<ushort4*>(&As[ar][32 + 4 * ah]) = l0.q[0];
            *reinterpret_cast<ushort4*>(&As[ar][40 + 4 * ah]) = l0.q[1];
            *reinterpret_cast<ushort4*>(&As[ar][48 + 4 * ah]) = l1.q[0];
            *reinterpret_cast<ushort4*>(&As[ar][56 + 4 * ah]) = l1.q[1];
        }
#pragma unroll
        for (int g = 0; g < 4; ++g) {
            ushort4 hv, lv;
            split4(pb[g], hv, lv);
            *reinterpret_cast<ushort4*>(&Bs[ar][8 * g + 4 * ah])      = hv;
            *reinterpret_cast<ushort4*>(&Bs[ar][32 + 8 * g + 4 * ah]) = lv;
        }
        __syncthreads();

        if (kt < 31) {
            const int ko = (kt + 1) * 32;
            if constexpr (MODE == 4) {
#pragma unroll
                for (int g = 0; g < 4; ++g)
                    pa[g] = *reinterpret_cast<const float4*>(Ap + ko + g * 4);
            } else {
                pah[0] = *reinterpret_cast<const u16x8*>(Aph + ko);
                pah[1] = *reinterpret_cast<const u16x8*>(Aph + ko + 8);
                pal[0] = *reinterpret_cast<const u16x8*>(Apl + ko);
                pal[1] = *reinterpret_cast<const u16x8*>(Apl + ko + 8);
            }
#pragma unroll
            for (int g = 0; g < 4; ++g)
                pb[g] = *reinterpret_cast<const float4*>(Wp + ko + g * 4);
        }

        FragU b_h[4], b_l[4];
#pragma unroll
        for (int ni = 0; ni < 4; ++ni) {
            const int row = wc * 64 + ni * 16 + l15;
            b_h[ni].u = *reinterpret_cast<const u16x8*>(&Bs[row][8 * lg]);
            b_l[ni].u = *reinterpret_cast<const u16x8*>(&Bs[row][32 + 8 * lg]);
        }
#pragma unroll
        for (int mi = 0; mi < 4; ++mi) {
            FragU a_h, a_l;
            const int row = wr * 64 + mi * 16 + l15;
            a_h.u = *reinterpret_cast<const u16x8*>(&As[row][8 * lg]);
            a_l.u = *reinterpret_cast<const u16x8*>(&As[row][32 + 8 * lg]);
#pragma unroll
            for (int ni = 0; ni < 4; ++ni) {
                f32x4 c = acc[mi][ni];
                c = __builtin_amdgcn_mfma_f32_16x16x32_bf16(a_h.b, b_h[ni].b, c, 0, 0, 0);
                c = __builtin_amdgcn_mfma_f32_16x16x32_bf16(a_h.b, b_l[ni].b, c, 0, 0, 0);
                c = __builtin_amdgcn_mfma_f32_16x16x32_bf16(a_l.b, b_h[ni].b, c, 0, 0, 0);
                acc[mi][ni] = c;
            }
        }
        __syncthreads();
    }

    if constexpr (MODE == 0) {
#pragma unroll
        for (int mi = 0; mi < 4; ++mi)
#pragma unroll
            for (int ni = 0; ni < 4; ++ni)
#pragma unroll
                for (int r = 0; r < 4; ++r) {
                    const int m = m0 + wr * 64 + mi * 16 + lg * 4 + r;
                    const int n = bx * 128 + wc * 64 + ni * 16 + l15;
                    Ofp[(size_t)m * DM + n] = acc[mi][ni][r];
                }
    } else if (wt == 2) {
#pragma unroll
        for (int mi = 0; mi < 4; ++mi)
#pragma unroll
            for (int ni = 0; ni < 4; ++ni) {
                ushort4 hv, lv;
                unsigned short* hp = (unsigned short*)&hv;
                unsigned short* lp = (unsigned short*)&lv;
#pragma unroll
                for (int r = 0; r < 4; ++r) split1(acc[mi][ni][r], hp[r], lp[r]);
                const int vrow = bx * 128 + wc * 64 + ni * 16 + l15;
                const size_t off = (size_t)vrow * SEQ + m0 + wr * 64 + mi * 16 + lg * 4;
                *reinterpret_cast<ushort4*>(&OVh[off]) = hv;
                *reinterpret_cast<ushort4*>(&OVl[off]) = lv;
            }
    } else {
        unsigned short* Oh = (wt == 0) ? OQh : OKh;
        unsigned short* Ol = (wt == 0) ? OQl : OKl;
        const int head = bx * 2 + wc;
        const float qsc = 0.1803368801f;   // 0.125 * log2(e)
#pragma unroll
        for (int mi = 0; mi < 4; ++mi)
#pragma unroll
            for (int r = 0; r < 4; ++r) {
                const int m   = m0 + wr * 64 + mi * 16 + lg * 4 + r;
                const int pos = positions[m];
#pragma unroll
                for (int ni = 0; ni < 4; ++ni) {
                    float val = acc[mi][ni][r];
                    const int d = ni * 16 + l15;
                    const float other = __shfl_xor(val, 1);
                    const float cc = cosT[pos * 32 + ni * 8 + (l15 >> 1)];
                    const float ss = sinT[pos * 32 + ni * 8 + (l15 >> 1)];
                    val = (d & 1) ? fmaf(other, ss, val * cc)
                                  : fmaf(other, -ss, val * cc);
                    if (wt == 0) val *= qsc;
                    unsigned short hh, ll;
                    split1(val, hh, ll);
                    const size_t off = ((size_t)head * SEQ + m) * DK + d;
                    Oh[off] = hh; Ol[off] = ll;
                }
            }
    }
}

// ---------------------------------------------------------------------------
// MFMA flash attention. QBLK=128, UNPAIRED: one qt per block, grid 512,
// heavy tiles first (qt = 31 - (r>>1)), 2 blocks/CU for TLP.
// LDS pitch 64 + XOR granule swizzle (phys granule = g ^ (row&7)):
// staging writes conflict-free, frag reads 2-way (free).
// ---------------------------------------------------------------------------
__global__ __launch_bounds__(256, 2)
void attn_mfma(const unsigned short* __restrict__ Qhi, const unsigned short* __restrict__ Qlo,
               const unsigned short* __restrict__ Khi, const unsigned short* __restrict__ Klo,
               const unsigned short* __restrict__ Vhi, const unsigned short* __restrict__ Vlo,
               unsigned short* __restrict__ Yh, unsigned short* __restrict__ Yl)
{
    __shared__ unsigned short KsH[64][64], KsL[64][64];
    __shared__ unsigned short VsH[64][64], VsL[64][64];

    const int t = threadIdx.x, lane = t & 63, w = t >> 6;
    const int bid = blockIdx.x;
    const int xcd = bid & 7, r_ = bid >> 3;
    const int h  = 2 * xcd + (r_ & 1);     // 2 heads per XCD (KV L2-resident)
    const int qt = 31 - (r_ >> 1);         // heavy q-tiles dispatched first
    const int l15 = lane & 15, lg = lane >> 4, dg = lg * 4;
    const int srow = t >> 2, q16 = t & 3;

    // swizzled write columns for this thread's 4 ushort4 pieces
    int wcol[4];
#pragma unroll
    for (int m = 0; m < 4; ++m) {
        const int g = (q16 >> 1) * 4 + m;
        wcol[m] = (((g ^ (srow & 7)) << 3) + ((q16 & 1) << 2));
    }

    const int K0 = 2 * qt;
    const int ktmax = K0 + 1;

    // Q fragments: frag u rows qt*128 + u*64 + w*16 + l15
    bf16x8 qh[2][2], ql[2][2];
#pragma unroll
    for (int u = 0; u < 2; ++u) {
        const size_t qrow = ((size_t)h * SEQ + (size_t)qt * 128 + u * 64 + w * 16 + l15) * DK;
#pragma unroll
        for (int c = 0; c < 2; ++c) {
            FragU uh, ul;
            uh.q[0] = *reinterpret_cast<const ushort4*>(&Qhi[qrow + c * 32 + dg]);
            uh.q[1] = *reinterpret_cast<const ushort4*>(&Qhi[qrow + c * 32 + 16 + dg]);
            ul.q[0] = *reinterpret_cast<const ushort4*>(&Qlo[qrow + c * 32 + dg]);
            ul.q[1] = *reinterpret_cast<const ushort4*>(&Qlo[qrow + c * 32 + 16 + dg]);
            qh[u][c] = uh.b; ql[u][c] = ul.b;
        }
    }

    f32x4 yacc[2][4];
#pragma unroll
    for (int u = 0; u < 2; ++u)
#pragma unroll
        for (int dt = 0; dt < 4; ++dt) yacc[u][dt] = (f32x4){0.f, 0.f, 0.f, 0.f};
    float m_run[2] = {-1e30f, -1e30f}, l_run[2] = {0.f, 0.f};

    u16x8 pf[8];
    {   // prefetch kt=0
        const size_t gK = ((size_t)h * SEQ + srow) * DK + q16 * 16;
        const size_t gV = ((size_t)h * DK + srow) * SEQ + q16 * 16;
        pf[0] = *reinterpret_cast<const u16x8*>(&Khi[gK]);
        pf[1] = *reinterpret_cast<const u16x8*>(&Khi[gK + 8]);
        pf[2] = *reinterpret_cast<const u16x8*>(&Klo[gK]);
        pf[3] = *reinterpret_cast<const u16x8*>(&Klo[gK + 8]);
        pf[4] = *reinterpret_cast<const u16x8*>(&Vhi[gV]);
        pf[5] = *reinterpret_cast<const u16x8*>(&Vhi[gV + 8]);
        pf[6] = *reinterpret_cast<const u16x8*>(&Vlo[gV]);
        pf[7] = *reinterpret_cast<const u16x8*>(&Vlo[gV + 8]);
    }

    for (int kt = 0; kt <= ktmax; ++kt) {
        __syncthreads();   // LDS free
        {
            FragU f;
            f.u = pf[0];
            *reinterpret_cast<ushort4*>(&KsH[srow][wcol[0]]) = f.q[0];
            *reinterpret_cast<ushort4*>(&KsH[srow][wcol[1]]) = f.q[1];
            f.u = pf[1];
            *reinterpret_cast<ushort4*>(&KsH[srow][wcol[2]]) = f.q[0];
            *reinterpret_cast<ushort4*>(&KsH[srow][wcol[3]]) = f.q[1];
            f.u = pf[2];
            *reinterpret_cast<ushort4*>(&KsL[srow][wcol[0]]) = f.q[0];
            *reinterpret_cast<ushort4*>(&KsL[srow][wcol[1]]) = f.q[1];
            f.u = pf[3];
            *reinterpret_cast<ushort4*>(&KsL[srow][wcol[2]]) = f.q[0];
            *reinterpret_cast<ushort4*>(&KsL[srow][wcol[3]]) = f.q[1];
            f.u = pf[4];
            *reinterpret_cast<ushort4*>(&VsH[srow][wcol[0]]) = f.q[0];
            *reinterpret_cast<ushort4*>(&VsH[srow][wcol[1]]) = f.q[1];
            f.u = pf[5];
            *reinterpret_cast<ushort4*>(&VsH[srow][wcol[2]]) = f.q[0];
            *reinterpret_cast<ushort4*>(&VsH[srow][wcol[3]]) = f.q[1];
            f.u = pf[6];
            *reinterpret_cast<ushort4*>(&VsL[srow][wcol[0]]) = f.q[0];
            *reinterpret_cast<ushort4*>(&VsL[srow][wcol[1]]) = f.q[1];
            f.u = pf[7];
            *reinterpret_cast<ushort4*>(&VsL[srow][wcol[2]]) = f.q[0];
            *reinterpret_cast<ushort4*>(&VsL[srow][wcol[3]]) = f.q[1];
        }
        __syncthreads();   // LDS ready

        if (kt < ktmax) {   // prefetch kt+1
            const size_t gK = ((size_t)h * SEQ + (size_t)(kt + 1) * 64 + srow) * DK + q16 * 16;
            const size_t gV = ((size_t)h * DK + srow) * SEQ + (size_t)(kt + 1) * 64 + q16 * 16;
            pf[0] = *reinterpret_cast<const u16x8*>(&Khi[gK]);
            pf[1] = *reinterpret_cast<const u16x8*>(&Khi[gK + 8]);
            pf[2] = *reinterpret_cast<const u16x8*>(&Klo[gK]);
            pf[3] = *reinterpret_cast<const u16x8*>(&Klo[gK + 8]);
            pf[4] = *reinterpret_cast<const u16x8*>(&Vhi[gV]);
            pf[5] = *reinterpret_cast<const u16x8*>(&Vhi[gV + 8]);
            pf[6] = *reinterpret_cast<const u16x8*>(&Vlo[gV]);
            pf[7] = *reinterpret_cast<const u16x8*>(&Vlo[gV + 8]);
        }

        const int mode0 = (kt < K0) ? 1 : ((kt == K0) ? 2 : 0);  // frag0
        const int mode1 = (kt <= K0) ? 1 : 2;                    // frag1
        const bool act0 = (mode0 != 0);

        // ---- S^T = K * Q^T, both q-frags share K fragment loads ----
        f32x4 st0[4], st1[4];
        __builtin_amdgcn_s_setprio(1);
#pragma unroll
        for (int ktile = 0; ktile < 4; ++ktile) {
            const bool sk0 = !act0 || (mode0 == 2 && ktile > w);
            const bool sk1 = (mode1 == 2 && ktile > w);
            f32x4 s0 = (f32x4){0.f, 0.f, 0.f, 0.f};
            f32x4 s1 = (f32x4){0.f, 0.f, 0.f, 0.f};
            if (!sk0 || !sk1) {
                const int rowK = ktile * 16 + l15;
                const int swk  = rowK & 7;
#pragma unroll
                for (int c = 0; c < 2; ++c) {
                    FragU kh, kl;
                    const int pcol = ((c * 4 + lg) ^ swk) << 3;
                    kh.u = *reinterpret_cast<const u16x8*>(&KsH[rowK][pcol]);
                    kl.u = *reinterpret_cast<const u16x8*>(&KsL[rowK][pcol]);
                    if (!sk0) {
                        s0 = __builtin_amdgcn_mfma_f32_16x16x32_bf16(kh.b, qh[0][c], s0, 0, 0, 0);
                        s0 = __builtin_amdgcn_mfma_f32_16x16x32_bf16(kh.b, ql[0][c], s0, 0, 0, 0);
                        s0 = __builtin_amdgcn_mfma_f32_16x16x32_bf16(kl.b, qh[0][c], s0, 0, 0, 0);
                    }
                    if (!sk1) {
                        s1 = __builtin_amdgcn_mfma_f32_16x16x32_bf16(kh.b, qh[1][c], s1, 0, 0, 0);
                        s1 = __builtin_amdgcn_mfma_f32_16x16x32_bf16(kh.b, ql[1][c], s1, 0, 0, 0);
                        s1 = __builtin_amdgcn_mfma_f32_16x16x32_bf16(kl.b, qh[1][c], s1, 0, 0, 0);
                    }
                }
            }
            st0[ktile] = sk0 ? (f32x4){-1e30f, -1e30f, -1e30f, -1e30f} : s0;
            st1[ktile] = sk1 ? (f32x4){-1e30f, -1e30f, -1e30f, -1e30f} : s1;
        }
        __builtin_amdgcn_s_setprio(0);

        if (mode0 == 2) {
#pragma unroll
            for (int ktile = 0; ktile < 4; ++ktile)
#pragma unroll
                for (int r = 0; r < 4; ++r)
                    if (ktile * 16 + dg + r > w * 16 + l15) st0[ktile][r] = -1e30f;
        }
        if (mode1 == 2) {
#pragma unroll
            for (int ktile = 0; ktile < 4; ++ktile)
#pragma unroll
                for (int r = 0; r < 4; ++r)
                    if (ktile * 16 + dg + r > w * 16 + l15) st1[ktile][r] = -1e30f;
        }

        // ---- online softmax (exp2 units, defer-max) ----
        bf16x8 pa0[2], pa1[2];
#pragma unroll
        for (int u = 0; u < 2; ++u) {
            if (u == 0 && !act0) continue;
            f32x4* st = (u == 0) ? st0 : st1;
            float rowmax = st[0][0];
#pragma unroll
            for (int ktile = 0; ktile < 4; ++ktile)
#pragma unroll
                for (int r = 0; r < 4; ++r) rowmax = fmaxf(rowmax, st[ktile][r]);
            rowmax = fmaxf(rowmax, __shfl_xor(rowmax, 16));
            rowmax = fmaxf(rowmax, __shfl_xor(rowmax, 32));
            if (!__all(rowmax <= m_run[u] + 11.5f)) {
                const float mnew = fmaxf(m_run[u], rowmax);
                const float factor = fexp2(m_run[u] - mnew);
                l_run[u] *= factor;
#pragma unroll
                for (int r = 0; r < 4; ++r) {
                    const float fr = __shfl(factor, (lg << 2) | r);
#pragma unroll
                    for (int dt = 0; dt < 4; ++dt) yacc[u][dt][r] *= fr;
                }
                m_run[u] = mnew;
            }
            float p[4][4]; float psum = 0.f;
#pragma unroll
            for (int ktile = 0; ktile < 4; ++ktile)
#pragma unroll
                for (int r = 0; r < 4; ++r) {
                    p[ktile][r] = fexp2(st[ktile][r] - m_run[u]);
                    psum += p[ktile][r];
                }
            psum += __shfl_xor(psum, 16);
            psum += __shfl_xor(psum, 32);
            l_run[u] += psum;
#pragma unroll
            for (int c = 0; c < 2; ++c) {
                FragU P;
                P.w[0] = cvtpk(p[2 * c][0],     p[2 * c][1]);
                P.w[1] = cvtpk(p[2 * c][2],     p[2 * c][3]);
                P.w[2] = cvtpk(p[2 * c + 1][0], p[2 * c + 1][1]);
                P.w[3] = cvtpk(p[2 * c + 1][2], p[2 * c + 1][3]);
                if (u == 0) pa0[c] = P.b; else pa1[c] = P.b;
            }
        }

        // ---- y += P * V (2-term), shared V loads ----
        __builtin_amdgcn_s_setprio(1);
#pragma unroll
        for (int dt = 0; dt < 4; ++dt) {
            const int rowV = dt * 16 + l15;
            const int swv  = rowV & 7;
#pragma unroll
            for (int c = 0; c < 2; ++c) {
                FragU vh, vl;
                const int pcol = ((c * 4 + lg) ^ swv) << 3;
                vh.u = *reinterpret_cast<const u16x8*>(&VsH[rowV][pcol]);
                vl.u = *reinterpret_cast<const u16x8*>(&VsL[rowV][pcol]);
                if (act0) {
                    yacc[0][dt] = __builtin_amdgcn_mfma_f32_16x16x32_bf16(pa0[c], vh.b, yacc[0][dt], 0, 0, 0);
                    yacc[0][dt] = __builtin_amdgcn_mfma_f32_16x16x32_bf16(pa0[c], vl.b, yacc[0][dt], 0, 0, 0);
                }
                yacc[1][dt] = __builtin_amdgcn_mfma_f32_16x16x32_bf16(pa1[c], vh.b, yacc[1][dt], 0, 0, 0);
                yacc[1][dt] = __builtin_amdgcn_mfma_f32_16x16x32_bf16(pa1[c], vl.b, yacc[1][dt], 0, 0, 0);
            }
        }
        __builtin_amdgcn_s_setprio(0);
    } // kt

    // ---- epilogue: y row = qt*128 + u*64 + w*16 + lg*4 + r ----
#pragma unroll
    for (int u = 0; u < 2; ++u) {
        const float inv = 1.0f / l_run[u];
#pragma unroll
        for (int r = 0; r < 4; ++r) {
            const float ir = __shfl(inv, (lg << 2) | r);
            const size_t row = (size_t)qt * 128 + u * 64 + w * 16 + lg * 4 + r;
#pragma unroll
            for (int dt = 0; dt < 4; ++dt) {
                unsigned short hh, ll;
                split1(yacc[u][dt][r] * ir, hh, ll);
                const size_t off = row * DM + h * DK + dt * 16 + l15;
                Yh[off] = hh; Yl[off] = ll;
            }
        }
    }
}

// ---------------------------------------------------------------------------
extern "C" void kernel_launch(void* const* d_in, const int* in_sizes, int n_in,
                              void* d_out, int out_size, void* d_ws, size_t ws_size,
                              hipStream_t stream)
{
    const float* x    = (const float*)d_in[0];
    const float* Wq   = (const float*)d_in[1];
    const float* Wk   = (const float*)d_in[2];
    const float* Wv   = (const float*)d_in[3];
    const float* Wo   = (const float*)d_in[4];
    const float* cosT = (const float*)d_in[5];
    const float* sinT = (const float*)d_in[6];
    const int*   pos  = (const int*)d_in[7];
    float* out = (float*)d_out;

    const size_t E = (size_t)SEQ * DM;
    unsigned short* qh = (unsigned short*)d_ws;
    unsigned short* ql = qh + E;
    unsigned short* kh = ql + E;
    unsigned short* kl = kh + E;
    unsigned short* vh = kl + E;
    unsigned short* vl = vh + E;
    unsigned short* yh = vl + E;
    unsigned short* yl = yh + E;

    gemm_mfma<4><<<dim3(768), dim3(256), 0, stream>>>(
        x, nullptr, nullptr, Wq, Wk, Wv,
        qh, ql, kh, kl, vh, vl, nullptr, cosT, sinT, pos);
    attn_mfma<<<dim3(512), dim3(256), 0, stream>>>(qh, ql, kh, kl, vh, vl, yh, yl);
    gemm_mfma<0><<<dim3(256), dim3(256), 0, stream>>>(
        nullptr, yh, yl, Wo, nullptr, nullptr,
        nullptr, nullptr, nullptr, nullptr, nullptr, nullptr, out, cosT, sinT, pos);
}